// Round 1
// baseline (76.768 us; speedup 1.0000x reference)
//
#include <hip/hip_runtime.h>
#include <math.h>

// PolicyNetwork3x3: conv(1->16,k2,valid) -> relu -> flatten(64, channel-major)
// -> fc(64->32)+relu -> {a: 32->16 relu -> 16->9 logits -> masked softmax,
//                        v: 32->8 relu -> 8->1 tanh}
// Batch of 1, ~3k MACs total: single block, single wave, LDS staging.

__global__ __launch_bounds__(64) void policy3x3_kernel(
    const float* __restrict__ x,      // 9   (3x3 board, values in {-1,0,1})
    const float* __restrict__ conv_w, // 16*1*2*2 = 64
    const float* __restrict__ fc_w,   // 32*64
    const float* __restrict__ fc_b,   // 32
    const float* __restrict__ a1_w,   // 16*32
    const float* __restrict__ a1_b,   // 16
    const float* __restrict__ a2_w,   // 9*16
    const float* __restrict__ a2_b,   // 9
    const float* __restrict__ v1_w,   // 8*32
    const float* __restrict__ v1_b,   // 8
    const float* __restrict__ v2_w,   // 8
    const float* __restrict__ v2_b,   // 1
    float* __restrict__ out)          // 10: prob[9] then value[1]
{
    __shared__ float s_x[9];
    __shared__ float s_f[64];     // relu(conv) flattened channel-major
    __shared__ float s_y[32];     // fc hidden
    __shared__ float s_ah[16];    // action hidden
    __shared__ float s_vh[8];     // value hidden
    __shared__ float s_logit[9];

    const int t = threadIdx.x;

    if (t < 9) s_x[t] = x[t];
    __syncthreads();

    // ---- conv + relu: one flat output element per lane ----
    // flat[oc*4 + oh*2 + ow], oc = t>>2
    {
        const int oc  = t >> 2;
        const int pos = t & 3;
        const int oh  = pos >> 1;
        const int ow  = pos & 1;
        float acc = 0.f;
#pragma unroll
        for (int kh = 0; kh < 2; ++kh)
#pragma unroll
            for (int kw = 0; kw < 2; ++kw)
                acc += s_x[(oh + kh) * 3 + (ow + kw)] * conv_w[oc * 4 + kh * 2 + kw];
        s_f[t] = fmaxf(acc, 0.f);
    }
    __syncthreads();

    // ---- fc: y[t] = relu(f . fc_w[t,:] + fc_b[t]), t < 32 ----
    if (t < 32) {
        float acc = fc_b[t];
#pragma unroll
        for (int k = 0; k < 64; ++k)
            acc += s_f[k] * fc_w[t * 64 + k];
        s_y[t] = fmaxf(acc, 0.f);
    }
    __syncthreads();

    // ---- a1 (lanes 0..15) and v1 (lanes 16..23) in parallel ----
    if (t < 16) {
        float acc = a1_b[t];
#pragma unroll
        for (int j = 0; j < 32; ++j)
            acc += s_y[j] * a1_w[t * 32 + j];
        s_ah[t] = fmaxf(acc, 0.f);
    } else if (t < 24) {
        const int i = t - 16;
        float acc = v1_b[i];
#pragma unroll
        for (int j = 0; j < 32; ++j)
            acc += s_y[j] * v1_w[i * 32 + j];
        s_vh[i] = fmaxf(acc, 0.f);
    }
    __syncthreads();

    // ---- a2 logits, lanes 0..8 ----
    if (t < 9) {
        float acc = a2_b[t];
#pragma unroll
        for (int i = 0; i < 16; ++i)
            acc += s_ah[i] * a2_w[t * 16 + i];
        s_logit[t] = acc;
    }
    __syncthreads();

    // ---- masked softmax (lane 0) and value head (lane 1) ----
    if (t == 0) {
        float maxa = s_logit[0];
#pragma unroll
        for (int c = 1; c < 9; ++c) maxa = fmaxf(maxa, s_logit[c]);
        float e[9];
        float sum = 0.f;
#pragma unroll
        for (int c = 0; c < 9; ++c) {
            // avail: cell not occupied (|x| != 1); x values are exact {-1,0,1}
            const float avail = (fabsf(s_x[c]) != 1.0f) ? 1.0f : 0.0f;
            e[c] = avail * __expf(s_logit[c] - maxa);
            sum += e[c];
        }
        const float inv = 1.0f / sum;
#pragma unroll
        for (int c = 0; c < 9; ++c) out[c] = e[c] * inv;
    } else if (t == 1) {
        float acc = v2_b[0];
#pragma unroll
        for (int i = 0; i < 8; ++i)
            acc += s_vh[i] * v2_w[i];
        out[9] = tanhf(acc);
    }
}

extern "C" void kernel_launch(void* const* d_in, const int* in_sizes, int n_in,
                              void* d_out, int out_size, void* d_ws, size_t ws_size,
                              hipStream_t stream) {
    (void)in_sizes; (void)n_in; (void)d_ws; (void)ws_size; (void)out_size;
    const float* x      = (const float*)d_in[0];
    const float* conv_w = (const float*)d_in[1];
    const float* fc_w   = (const float*)d_in[2];
    const float* fc_b   = (const float*)d_in[3];
    const float* a1_w   = (const float*)d_in[4];
    const float* a1_b   = (const float*)d_in[5];
    const float* a2_w   = (const float*)d_in[6];
    const float* a2_b   = (const float*)d_in[7];
    const float* v1_w   = (const float*)d_in[8];
    const float* v1_b   = (const float*)d_in[9];
    const float* v2_w   = (const float*)d_in[10];
    const float* v2_b   = (const float*)d_in[11];
    float* out = (float*)d_out;

    hipLaunchKernelGGL(policy3x3_kernel, dim3(1), dim3(64), 0, stream,
                       x, conv_w, fc_w, fc_b, a1_w, a1_b, a2_w, a2_b,
                       v1_w, v1_b, v2_w, v2_b, out);
}